// Round 5
// baseline (419.926 us; speedup 1.0000x reference)
//
#include <hip/hip_runtime.h>
#include <math.h>

typedef __bf16 bf16x8 __attribute__((ext_vector_type(8)));
typedef float floatx4 __attribute__((ext_vector_type(4)));
typedef unsigned short ushort8_t __attribute__((ext_vector_type(8)));

#define BSZ 8
#define SEQ 2048
#define DIM 512
#define BKEY 32
#define BQ 128   // 8 waves x 16 rows share each staged K/V tile
#define NSLOT 70 // partial slots per batch (items with t>=2)

__device__ __forceinline__ unsigned short f2bf(float f) {
    unsigned int u = __float_as_uint(f);
    u += 0x7fffu + ((u >> 16) & 1u);   // RNE
    return (unsigned short)(u >> 16);
}
__device__ __forceinline__ float bf2f(unsigned short s) {
    return __uint_as_float(((unsigned int)s) << 16);
}

// async global->LDS, 16B per lane. LDS dest is wave-uniform base + lane*16,
// so LDS layout is linear in chunk index; the bank swizzle is applied by
// permuting the *global* source address within its segment.
#define ASYNC16(g, l) __builtin_amdgcn_global_load_lds( \
    (const __attribute__((address_space(1))) unsigned int*)(g), \
    (__attribute__((address_space(3))) unsigned int*)(l), 16, 0, 0)

// ---------- pre-pass 1: K fp32 -> bf16 row-major [b][k][d] ----------
__global__ __launch_bounds__(256) void conv_k(const float* __restrict__ K,
                                              unsigned short* __restrict__ Kb) {
    size_t i = ((size_t)blockIdx.x * 256 + threadIdx.x) * 8;
    float4 a = *(const float4*)(K + i);
    float4 b = *(const float4*)(K + i + 4);
    ushort8_t u;
    u[0]=f2bf(a.x); u[1]=f2bf(a.y); u[2]=f2bf(a.z); u[3]=f2bf(a.w);
    u[4]=f2bf(b.x); u[5]=f2bf(b.y); u[6]=f2bf(b.z); u[7]=f2bf(b.w);
    *(ushort8_t*)(Kb + i) = u;
}

// ---------- pre-pass 2: V fp32 [b][k][d] -> bf16 tiled-transposed ----------
// Vt[(b*64 + ktile)*512*32 + d*32 + key] : each 32-key tile contiguous (32KB)
__global__ __launch_bounds__(256) void trans_v(const float* __restrict__ V,
                                               unsigned short* __restrict__ Vt) {
    __shared__ unsigned short T[BKEY][DIM + 8];
    const int bid = blockIdx.x;            // 8*64
    const int b = bid & 7, kb = bid >> 3;
    const float* src = V + ((size_t)b * SEQ + (size_t)kb * BKEY) * DIM;
    const int tid = threadIdx.x;
    #pragma unroll
    for (int i = 0; i < 16; ++i) {
        const int idx = i * 256 + tid;     // float4 idx, 4096 total
        const int key = idx >> 7;
        const int d = (idx & 127) * 4;
        float4 x = *(const float4*)(src + (size_t)key * DIM + d);
        T[key][d]   = f2bf(x.x);
        T[key][d+1] = f2bf(x.y);
        T[key][d+2] = f2bf(x.z);
        T[key][d+3] = f2bf(x.w);
    }
    __syncthreads();
    unsigned short* dst = Vt + (size_t)(b * (SEQ / BKEY) + kb) * DIM * BKEY;
    #pragma unroll
    for (int i = 0; i < 8; ++i) {
        const int cidx = i * 256 + tid;    // 16B chunk 0..2047
        const int d = cidx >> 2;
        const int kc = cidx & 3;
        ushort8_t v;
        #pragma unroll
        for (int k2 = 0; k2 < 8; ++k2) v[k2] = T[kc * 8 + k2][d];
        *(ushort8_t*)(dst + cidx * 8) = v;
    }
}

// Work decomposition (per batch, q-tiles of 128 rows, k-tiles of 32 keys):
//   q-tile t in [0,16) needs nk = 4t+4 k-tiles. Chunks of <=8 k-tiles
//   (always a multiple of 2 tiles -> pair-processing is safe):
//   items per t = (t+2)>>1  => 72 items/batch; j<70 are t>=2 (split).

template <int SPLIT>
__global__ __launch_bounds__(512, 2)
void attn_fwd(const float* __restrict__ Q,
              const unsigned short* __restrict__ Kb,
              const unsigned short* __restrict__ Vt,
              unsigned short* __restrict__ PartO,
              float* __restrict__ Pml,
              float* __restrict__ O)
{
    // K/V both double-buffered AND both tiles of a pair resident:
    // per 64-key pair: one softmax, one P round trip, 4 barriers.
    __shared__ unsigned short Ksh[2][BKEY * DIM];  // chunk i <-> (row=i>>6, cc=i&63), holds ch=cc^(row&7)
    __shared__ unsigned short Vsh[2][DIM * BKEY];  // chunk i <-> (d=i>>2, cc=i&3), holds kc=cc^(d&3)
    __shared__ unsigned short Psh[8 * 16 * 64];    // per-wave 16 rows x 64 cols, chunk^=(row&7)

    const int tid  = threadIdx.x;
    const int lane = tid & 63;
    const int wv   = tid >> 6;                    // 0..7
    const int ml   = lane & 15;
    const int quad = lane >> 4;

    const int bid = blockIdx.x;
    const int b   = bid & 7;                      // batch -> XCD L2 locality
    const int j   = bid >> 3;
    int t, c;
    if (SPLIT) {
        t = 15; c = j;
        while (true) { const int cnt = (t + 2) >> 1; if (c < cnt) break; c -= cnt; --t; }
    } else { t = 15 - j; c = 0; }
    const int kt0 = c * 8;
    const int nk  = 4 * t + 4;
    const int kt1 = min(kt0 + 8, nk);             // kt1-kt0 in {4,8}: even
    const bool is_split = SPLIT && (t >= 2);
    const int q0 = t * BQ;
    const int kdiag = 4 * t;                      // first diagonal-crossing k-tile

    const float* Qb = Q + (size_t)b * SEQ * DIM;
    const unsigned short* Kbb = Kb + (size_t)b * SEQ * DIM;
    const unsigned short* Vtb = Vt + (size_t)b * SEQ * DIM;   // tiled
    float* Ob = O + (size_t)b * SEQ * DIM;

    // ---- Q fragments, A-layout: A[m=lane&15][k=quad*8+j] ----
    bf16x8 qf[16];
    {
        const float* qp = Qb + (size_t)(q0 + wv * 16 + ml) * DIM + quad * 8;
        #pragma unroll
        for (int kc = 0; kc < 16; ++kc) {
            float4 x = *(const float4*)(qp + kc * 32);
            float4 y = *(const float4*)(qp + kc * 32 + 4);
            union { bf16x8 v; unsigned short s[8]; } u;
            u.s[0]=f2bf(x.x); u.s[1]=f2bf(x.y); u.s[2]=f2bf(x.z); u.s[3]=f2bf(x.w);
            u.s[4]=f2bf(y.x); u.s[5]=f2bf(y.y); u.s[6]=f2bf(y.z); u.s[7]=f2bf(y.w);
            qf[kc] = u.v;
        }
    }
    // pin the Q loads before any staging so in-loop vmcnt counting sees only stages
    asm volatile("" ::: "memory");

    floatx4 acc[32];
    #pragma unroll
    for (int i = 0; i < 32; ++i) acc[i] = (floatx4){0.f, 0.f, 0.f, 0.f};
    float mrun[4] = {-INFINITY, -INFINITY, -INFINITY, -INFINITY};
    float lrun[4] = {0.f, 0.f, 0.f, 0.f};

    const float CS = 1.4426950408889634f * 0.04419417382415922f; // log2(e)/sqrt(512)

    // stage K tile kt_ into buf_ (4 x 16B per thread, swizzled source)
    #define STAGE_K(buf_, kt_) do { \
        const unsigned short* Kt_ = Kbb + (size_t)(kt_) * (BKEY * DIM); \
        unsigned short* Kd_ = &Ksh[(buf_)][0]; \
        _Pragma("unroll") \
        for (int i_ = 0; i_ < 4; ++i_) { \
            const int ci_  = i_ * 512 + tid; \
            const int row_ = ci_ >> 6; \
            const int ch_  = (ci_ & 63) ^ (row_ & 7); \
            ASYNC16(Kt_ + (size_t)row_ * DIM + ch_ * 8, Kd_ + ci_ * 8); \
        } } while (0)
    // stage V tile kt_ from contiguous pre-transposed tile
    #define STAGE_V(buf_, kt_) do { \
        const unsigned short* Vt_ = Vtb + (size_t)(kt_) * (DIM * BKEY); \
        unsigned short* Vd_ = &Vsh[(buf_)][0]; \
        _Pragma("unroll") \
        for (int i_ = 0; i_ < 4; ++i_) { \
            const int ci_ = i_ * 512 + tid; \
            const int d_  = ci_ >> 2; \
            const int kc_ = (ci_ & 3) ^ (d_ & 3); \
            ASYNC16(Vt_ + d_ * BKEY + kc_ * 8, Vd_ + ci_ * 8); \
        } } while (0)

    // ---- prologue: K pair + V pair in flight; wait K pair only ----
    STAGE_K(0, kt0); STAGE_K(1, kt0 + 1);
    STAGE_V(0, kt0); STAGE_V(1, kt0 + 1);
    asm volatile("s_waitcnt vmcnt(8)" ::: "memory");   // K pair done (V pair flying)
    __builtin_amdgcn_s_barrier();                      // K visible to all waves

    for (int kt = kt0; kt < kt1; kt += 2) {
        const int k0 = kt * BKEY;
        const bool havenxt = (kt + 2 < kt1);

        // ---- S = Q K^T over BOTH tiles: 4 independent chains, 64 MFMA ----
        const unsigned short* KsA = &Ksh[0][0];
        const unsigned short* KsB = &Ksh[1][0];
        floatx4 s[4];
        #pragma unroll
        for (int i = 0; i < 4; ++i) s[i] = (floatx4){0.f, 0.f, 0.f, 0.f};
        const int sw = ml & 7;
        __builtin_amdgcn_s_setprio(1);
        #pragma unroll
        for (int kc = 0; kc < 16; ++kc) {
            const int off = ((kc * 4 + quad) ^ sw) << 3;
            bf16x8 a0 = *(bf16x8*)&KsA[ml * DIM + off];
            bf16x8 a1 = *(bf16x8*)&KsA[(16 + ml) * DIM + off];
            bf16x8 b0 = *(bf16x8*)&KsB[ml * DIM + off];
            bf16x8 b1 = *(bf16x8*)&KsB[(16 + ml) * DIM + off];
            s[0] = __builtin_amdgcn_mfma_f32_16x16x32_bf16(qf[kc], a0, s[0], 0, 0, 0);
            s[1] = __builtin_amdgcn_mfma_f32_16x16x32_bf16(qf[kc], a1, s[1], 0, 0, 0);
            s[2] = __builtin_amdgcn_mfma_f32_16x16x32_bf16(qf[kc], b0, s[2], 0, 0, 0);
            s[3] = __builtin_amdgcn_mfma_f32_16x16x32_bf16(qf[kc], b1, s[3], 0, 0, 0);
        }
        __builtin_amdgcn_s_setprio(0);

        // Ksh pair free (all waves consumed operands)
        asm volatile("" ::: "memory");
        __builtin_amdgcn_s_barrier();
        if (havenxt) { STAGE_K(0, kt + 2); STAGE_K(1, kt + 3); }

        // ---- mask + scale in place (s becomes z, in log2 domain) ----
        // s[nt] cols: nt=0: k0+ml | nt=1: k0+16+ml | nt=2: k0+32+ml | nt=3: k0+48+ml
        if (kt + 1 >= kdiag) {
            #pragma unroll
            for (int r = 0; r < 4; ++r) {
                const int qg = q0 + wv * 16 + quad * 4 + r;
                s[0][r] = (k0 + ml > qg)      ? -INFINITY : s[0][r] * CS;
                s[1][r] = (k0 + 16 + ml > qg) ? -INFINITY : s[1][r] * CS;
                s[2][r] = (k0 + 32 + ml > qg) ? -INFINITY : s[2][r] * CS;
                s[3][r] = (k0 + 48 + ml > qg) ? -INFINITY : s[3][r] * CS;
            }
        } else {
            #pragma unroll
            for (int r = 0; r < 4; ++r) {
                s[0][r] *= CS; s[1][r] *= CS; s[2][r] *= CS; s[3][r] *= CS;
            }
        }

        // ---- online softmax, one reduce per 64 keys; defer-max (THR=8 log2) ----
        float al[4];
        #pragma unroll
        for (int r = 0; r < 4; ++r) {
            float v = fmaxf(fmaxf(s[0][r], s[1][r]), fmaxf(s[2][r], s[3][r]));
            v = fmaxf(v, __shfl_xor(v, 1, 64));
            v = fmaxf(v, __shfl_xor(v, 2, 64));
            v = fmaxf(v, __shfl_xor(v, 4, 64));
            v = fmaxf(v, __shfl_xor(v, 8, 64));
            const float d = v - mrun[r];
            const bool up = d > 8.0f;              // defer small max growth
            al[r]   = up ? __builtin_amdgcn_exp2f(-d) : 1.0f;
            mrun[r] = up ? v : mrun[r];
        }
        #pragma unroll
        for (int r = 0; r < 4; ++r) {
            s[0][r] = __builtin_amdgcn_exp2f(s[0][r] - mrun[r]);
            s[1][r] = __builtin_amdgcn_exp2f(s[1][r] - mrun[r]);
            s[2][r] = __builtin_amdgcn_exp2f(s[2][r] - mrun[r]);
            s[3][r] = __builtin_amdgcn_exp2f(s[3][r] - mrun[r]);
            float rs = (s[0][r] + s[1][r]) + (s[2][r] + s[3][r]);
            rs += __shfl_xor(rs, 1, 64);
            rs += __shfl_xor(rs, 2, 64);
            rs += __shfl_xor(rs, 4, 64);
            rs += __shfl_xor(rs, 8, 64);
            lrun[r] = lrun[r] * al[r] + rs;
        }

        if (al[0] < 1.f || al[1] < 1.f || al[2] < 1.f || al[3] < 1.f) {
            #pragma unroll
            for (int nt = 0; nt < 32; ++nt) {
                acc[nt][0] *= al[0]; acc[nt][1] *= al[1];
                acc[nt][2] *= al[2]; acc[nt][3] *= al[3];
            }
        }

        // ---- P (16x64): C-layout -> A-layout via per-wave LDS round trip ----
        unsigned short* Pw = &Psh[wv * (16 * 64)];
        #pragma unroll
        for (int nt = 0; nt < 4; ++nt) {
            #pragma unroll
            for (int r = 0; r < 4; ++r) {
                const int row = quad * 4 + r, col = nt * 16 + ml;
                Pw[row * 64 + ((((col >> 3) ^ (row & 7)) << 3) | (col & 7))] = f2bf(s[nt][r]);
            }
        }
        asm volatile("s_waitcnt lgkmcnt(0)" ::: "memory");
        bf16x8 pf0 = *(bf16x8*)&Pw[ml * 64 + ((quad ^ (ml & 7)) << 3)];
        bf16x8 pf1 = *(bf16x8*)&Pw[ml * 64 + (((4 + quad) ^ (ml & 7)) << 3)];

        // ---- wait V pair (covered by 64 QK MFMA + softmax) ----
        if (havenxt) { asm volatile("s_waitcnt vmcnt(8)" ::: "memory"); }  // K pair stays in flight
        else         { asm volatile("s_waitcnt vmcnt(0)" ::: "memory"); }
        __builtin_amdgcn_s_barrier();      // V pair visible

        // ---- O += P V over both tiles: 64 MFMA ----
        const unsigned short* VsA = &Vsh[0][0];
        const unsigned short* VsB = &Vsh[1][0];
        __builtin_amdgcn_s_setprio(1);
        #pragma unroll
        for (int nt = 0; nt < 32; ++nt) {
            const int drow = nt * 16 + ml;
            const int off = drow * BKEY + ((quad ^ (drow & 3)) << 3);
            bf16x8 vfA = *(bf16x8*)&VsA[off];
            bf16x8 vfB = *(bf16x8*)&VsB[off];
            acc[nt] = __builtin_amdgcn_mfma_f32_16x16x32_bf16(pf0, vfA, acc[nt], 0, 0, 0);
            acc[nt] = __builtin_amdgcn_mfma_f32_16x16x32_bf16(pf1, vfB, acc[nt], 0, 0, 0);
        }
        __builtin_amdgcn_s_setprio(0);

        if (havenxt) {
            asm volatile("" ::: "memory");
            __builtin_amdgcn_s_barrier();                     // Vsh pair free
            STAGE_V(0, kt + 2); STAGE_V(1, kt + 3);
            asm volatile("s_waitcnt vmcnt(8)" ::: "memory");  // K pair done (V pair flying)
            __builtin_amdgcn_s_barrier();                     // K visible
        }
    }
    #undef STAGE_K
    #undef STAGE_V

    if (!is_split) {
        float inv[4];
        #pragma unroll
        for (int r = 0; r < 4; ++r) inv[r] = 1.f / lrun[r];
        #pragma unroll
        for (int nt = 0; nt < 32; ++nt) {
            #pragma unroll
            for (int r = 0; r < 4; ++r) {
                const int row = q0 + wv * 16 + quad * 4 + r;
                Ob[(size_t)row * DIM + nt * 16 + ml] = acc[nt][r] * inv[r];
            }
        }
    } else {
        const size_t slot = (size_t)(b * NSLOT + j);
        unsigned short* po = PartO + slot * (BQ * DIM);
        #pragma unroll
        for (int nt = 0; nt < 32; ++nt) {
            #pragma unroll
            for (int r = 0; r < 4; ++r) {
                const int prow = wv * 16 + quad * 4 + r;
                po[prow * DIM + nt * 16 + ml] = f2bf(acc[nt][r]);
            }
        }
        if (ml == 0) {
            #pragma unroll
            for (int r = 0; r < 4; ++r) {
                const int prow = wv * 16 + quad * 4 + r;
                Pml[slot * 256 + prow * 2]     = mrun[r];
                Pml[slot * 256 + prow * 2 + 1] = lrun[r];
            }
        }
    }
}

// ---------- merge pass: combine 2..8 chunk partials per (b, t>=2, rowgroup) ----------
__global__ __launch_bounds__(256)
void attn_merge(const unsigned short* __restrict__ PartO,
                const float* __restrict__ Pml,
                float* __restrict__ O)
{
    const int bid = blockIdx.x;            // 8 * 14 * 4
    const int b = bid & 7;
    const int u = bid >> 3;                // 0..55
    const int t = 2 + (u >> 2);            // 2..15
    const int rg = u & 3;                  // 32-row group of the 128-row tile
    const int nc = (t + 2) >> 1;           // 2..8 chunks
    int j0 = 0;
    for (int tp = 15; tp > t; --tp) j0 += (tp + 2) >> 1;

    const int r   = threadIdx.x >> 3;      // 0..31
    const int row = rg * 32 + r;           // 0..127 within q-tile
    const int d0  = (threadIdx.x & 7) * 64;

    float M = -INFINITY;
    for (int cc = 0; cc < nc; ++cc) {
        const size_t slot = (size_t)(b * NSLOT + j0 + cc);
        M = fmaxf(M, Pml[slot * 256 + row * 2]);
    }
    float L = 0.f;
    for (int cc = 0; cc < nc; ++cc) {
        const size_t slot = (size_t)(b * NSLOT + j0 + cc);
        L += Pml[slot * 256 + row * 2 + 1] *
             __builtin_amdgcn_exp2f(Pml[slot * 256 + row * 2] - M);
    }

    float o[64];
    #pragma unroll
    for (int i = 0; i < 64; ++i) o[i] = 0.f;
    for (int cc = 0; cc < nc; ++cc) {
        const size_t slot = (size_t)(b * NSLOT + j0 + cc);
        const float w = __builtin_amdgcn_exp2f(Pml[slot * 256 + row * 2] - M);
        const unsigned short* po = PartO + slot * (BQ * DIM) + (size_t)row * DIM + d0;
        #pragma unroll
        for (int i = 0; i < 8; ++i) {
            ushort8_t v = *(const ushort8_t*)(po + i * 8);
            #pragma unroll
            for (int k2 = 0; k2 < 8; ++k2) o[i * 8 + k2] += w * bf2f(v[k2]);
        }
    }
    const float invL = 1.f / L;
    float* out = O + ((size_t)b * SEQ + (size_t)t * BQ + row) * DIM + d0;
    #pragma unroll
    for (int i = 0; i < 16; ++i) {
        float4 v4 = { o[i*4] * invL, o[i*4+1] * invL, o[i*4+2] * invL, o[i*4+3] * invL };
        *(float4*)(out + i * 4) = v4;
    }
}

extern "C" void kernel_launch(void* const* d_in, const int* in_sizes, int n_in,
                              void* d_out, int out_size, void* d_ws, size_t ws_size,
                              hipStream_t stream) {
    const float* Q = (const float*)d_in[0];
    const float* K = (const float*)d_in[1];
    const float* V = (const float*)d_in[2];
    float* Out = (float*)d_out;

    const size_t elems = (size_t)BSZ * SEQ * DIM;                 // 8.39M
    unsigned short* Kb = (unsigned short*)d_ws;
    unsigned short* Vt = Kb + elems;
    unsigned short* PartO = Vt + elems;
    float* Pml = (float*)(PartO + (size_t)BSZ * NSLOT * BQ * DIM);

    const size_t need_split = 2 * elems * 2                           // Kb + Vt
                            + (size_t)BSZ * NSLOT * BQ * DIM * 2      // PartO bf16
                            + (size_t)BSZ * NSLOT * 256 * 4;          // Pml
    conv_k<<<dim3(elems / 8 / 256), dim3(256), 0, stream>>>(K, Kb);
    trans_v<<<dim3(BSZ * (SEQ / BKEY)), dim3(256), 0, stream>>>(V, Vt);

    if (ws_size >= need_split) {
        attn_fwd<1><<<dim3(BSZ * 72), dim3(512), 0, stream>>>(Q, Kb, Vt, PartO, Pml, Out);
        attn_merge<<<dim3(BSZ * 14 * 4), dim3(256), 0, stream>>>(PartO, Pml, Out);
    } else {
        attn_fwd<0><<<dim3(BSZ * 16), dim3(512), 0, stream>>>(Q, Kb, Vt, PartO, Pml, Out);
    }
}

// Round 6
// 315.666 us; speedup vs baseline: 1.3303x; 1.3303x over previous
//
#include <hip/hip_runtime.h>
#include <math.h>

typedef __bf16 bf16x8 __attribute__((ext_vector_type(8)));
typedef float floatx4 __attribute__((ext_vector_type(4)));
typedef unsigned short ushort8_t __attribute__((ext_vector_type(8)));

#define BSZ 8
#define SEQ 2048
#define DIM 512
#define BKEY 32
#define BQ 128   // 8 waves x 16 rows share each staged K/V tile

__device__ __forceinline__ unsigned short f2bf(float f) {
    unsigned int u = __float_as_uint(f);
    u += 0x7fffu + ((u >> 16) & 1u);   // RNE
    return (unsigned short)(u >> 16);
}
__device__ __forceinline__ float bf2f(unsigned short s) {
    return __uint_as_float(((unsigned int)s) << 16);
}

// async global->LDS, 16B per lane. LDS dest is wave-uniform base + lane*16,
// so LDS layout is linear in chunk index; the bank swizzle is applied by
// permuting the *global* source address within its segment.
#define ASYNC16(g, l) __builtin_amdgcn_global_load_lds( \
    (const __attribute__((address_space(1))) unsigned int*)(g), \
    (__attribute__((address_space(3))) unsigned int*)(l), 16, 0, 0)

// ---------- fused pre-pass: K fp32->bf16 rowmajor  +  V fp32->bf16 tiled-T ----------
// blocks [0,4096): conv K.  blocks [4096,4608): transpose V.
// Vt[(b*64 + ktile)*512*32 + d*32 + key] : each 32-key tile contiguous (32KB)
__global__ __launch_bounds__(256) void prep_kv(const float* __restrict__ K,
                                               const float* __restrict__ V,
                                               unsigned short* __restrict__ Kb,
                                               unsigned short* __restrict__ Vt) {
    if (blockIdx.x < 4096) {
        size_t i = ((size_t)blockIdx.x * 256 + threadIdx.x) * 8;
        float4 a = *(const float4*)(K + i);
        float4 b = *(const float4*)(K + i + 4);
        ushort8_t u;
        u[0]=f2bf(a.x); u[1]=f2bf(a.y); u[2]=f2bf(a.z); u[3]=f2bf(a.w);
        u[4]=f2bf(b.x); u[5]=f2bf(b.y); u[6]=f2bf(b.z); u[7]=f2bf(b.w);
        *(ushort8_t*)(Kb + i) = u;
        return;
    }
    __shared__ unsigned short T[BKEY][DIM + 8];
    const int bid = blockIdx.x - 4096;     // 8*64
    const int b = bid & 7, kb = bid >> 3;
    const float* src = V + ((size_t)b * SEQ + (size_t)kb * BKEY) * DIM;
    const int tid = threadIdx.x;
    #pragma unroll
    for (int i = 0; i < 16; ++i) {
        const int idx = i * 256 + tid;     // float4 idx, 4096 total
        const int key = idx >> 7;
        const int d = (idx & 127) * 4;
        float4 x = *(const float4*)(src + (size_t)key * DIM + d);
        T[key][d]   = f2bf(x.x);
        T[key][d+1] = f2bf(x.y);
        T[key][d+2] = f2bf(x.z);
        T[key][d+3] = f2bf(x.w);
    }
    __syncthreads();
    unsigned short* dst = Vt + (size_t)(b * (SEQ / BKEY) + kb) * DIM * BKEY;
    #pragma unroll
    for (int i = 0; i < 8; ++i) {
        const int cidx = i * 256 + tid;    // 16B chunk 0..2047
        const int d = cidx >> 2;
        const int kc = cidx & 3;
        ushort8_t v;
        #pragma unroll
        for (int k2 = 0; k2 < 8; ++k2) v[k2] = T[kc * 8 + k2][d];
        *(ushort8_t*)(dst + cidx * 8) = v;
    }
}

// Work decomposition (per batch, q-tiles of 128 rows, k-tiles of 32 keys):
//   q-tile t in [0,16) needs nk = 4t+4 k-tiles. Chunks of <=CH k-tiles,
//   cnt(t)=ceil(nk/CH); enumerated t descending (big chunks first), c ascending.
//   CH=6: 96 items/batch (768 blocks = 3.0 rounds/CU, zero tail);
//   CH=8: 72 items/batch (R4 fallback). Unsplit items (single chunk) sit at the
//   end of the enumeration, so split items occupy j in [0, NSLOT).

template <int SPLIT, int CH, int NSLOT>
__global__ __launch_bounds__(512, 2)
void attn_fwd(const float* __restrict__ Q,
              const unsigned short* __restrict__ Kb,
              const unsigned short* __restrict__ Vt,
              unsigned short* __restrict__ PartO,
              float* __restrict__ Pml,
              float* __restrict__ O)
{
    // fully double-buffered tiles: counted vmcnt, 2 barriers per phase
    __shared__ unsigned short Ksh[2][BKEY * DIM];  // chunk i <-> (row=i>>6, cc=i&63), holds ch=cc^(row&7)
    __shared__ unsigned short Vsh[2][DIM * BKEY];  // chunk i <-> (d=i>>2, cc=i&3), holds kc=cc^(d&3)
    __shared__ unsigned short Psh[8 * 16 * BKEY];

    const int tid  = threadIdx.x;
    const int lane = tid & 63;
    const int wv   = tid >> 6;                    // 0..7
    const int ml   = lane & 15;
    const int quad = lane >> 4;

    const int bid = blockIdx.x;
    const int b   = bid & 7;                      // batch -> XCD L2 locality
    const int j   = bid >> 3;
    int t, c;
    if (SPLIT) {
        t = 15; c = j;
        while (true) { const int cnt = (4 * t + 4 + CH - 1) / CH; if (c < cnt) break; c -= cnt; --t; }
    } else { t = 15 - j; c = 0; }
    const int nk  = 4 * t + 4;
    const int kt0 = c * CH;
    const int kt1 = SPLIT ? min(kt0 + CH, nk) : nk;
    const bool is_split = SPLIT && (nk > CH);
    const int q0 = t * BQ;
    const int kdiag = 4 * t;                      // first diagonal-crossing k-tile

    const float* Qb = Q + (size_t)b * SEQ * DIM;
    const unsigned short* Kbb = Kb + (size_t)b * SEQ * DIM;
    const unsigned short* Vtb = Vt + (size_t)b * SEQ * DIM;   // tiled
    float* Ob = O + (size_t)b * SEQ * DIM;

    // ---- Q fragments, A-layout: A[m=lane&15][k=quad*8+j] ----
    bf16x8 qf[16];
    {
        const float* qp = Qb + (size_t)(q0 + wv * 16 + ml) * DIM + quad * 8;
        #pragma unroll
        for (int kc = 0; kc < 16; ++kc) {
            float4 x = *(const float4*)(qp + kc * 32);
            float4 y = *(const float4*)(qp + kc * 32 + 4);
            union { bf16x8 v; unsigned short s[8]; } u;
            u.s[0]=f2bf(x.x); u.s[1]=f2bf(x.y); u.s[2]=f2bf(x.z); u.s[3]=f2bf(x.w);
            u.s[4]=f2bf(y.x); u.s[5]=f2bf(y.y); u.s[6]=f2bf(y.z); u.s[7]=f2bf(y.w);
            qf[kc] = u.v;
        }
    }
    // pin the Q loads before any staging so in-loop vmcnt counting sees only stages
    asm volatile("" ::: "memory");

    floatx4 acc[32];
    #pragma unroll
    for (int i = 0; i < 32; ++i) acc[i] = (floatx4){0.f, 0.f, 0.f, 0.f};
    // finite "minus infinity": keeps exp2(-INF - mrun) == 0 even for rows whose
    // entire chunk is causally masked (possible at CH=6), avoiding NaN.
    float mrun[4] = {-1e30f, -1e30f, -1e30f, -1e30f};
    float lrun[4] = {0.f, 0.f, 0.f, 0.f};

    const float CS = 1.4426950408889634f * 0.04419417382415922f; // log2(e)/sqrt(512)

    // stage K tile kt_ into buf_ (4 x 16B per thread, swizzled source)
    #define STAGE_K(buf_, kt_) do { \
        const unsigned short* Kt_ = Kbb + (size_t)(kt_) * (BKEY * DIM); \
        unsigned short* Kd_ = &Ksh[(buf_)][0]; \
        _Pragma("unroll") \
        for (int i_ = 0; i_ < 4; ++i_) { \
            const int ci_  = i_ * 512 + tid; \
            const int row_ = ci_ >> 6; \
            const int ch_  = (ci_ & 63) ^ (row_ & 7); \
            ASYNC16(Kt_ + (size_t)row_ * DIM + ch_ * 8, Kd_ + ci_ * 8); \
        } } while (0)
    // stage V tile kt_ from contiguous pre-transposed tile
    #define STAGE_V(buf_, kt_) do { \
        const unsigned short* Vt_ = Vtb + (size_t)(kt_) * (DIM * BKEY); \
        unsigned short* Vd_ = &Vsh[(buf_)][0]; \
        _Pragma("unroll") \
        for (int i_ = 0; i_ < 4; ++i_) { \
            const int ci_ = i_ * 512 + tid; \
            const int d_  = ci_ >> 2; \
            const int kc_ = (ci_ & 3) ^ (d_ & 3); \
            ASYNC16(Vt_ + d_ * BKEY + kc_ * 8, Vd_ + ci_ * 8); \
        } } while (0)

    // ---- prologue: K[kt0]+V[kt0] in flight into buf0; wait K only ----
    STAGE_K(0, kt0);
    STAGE_V(0, kt0);
    asm volatile("s_waitcnt vmcnt(4)" ::: "memory");   // K[kt0] done (V flying)
    __builtin_amdgcn_s_barrier();                      // K visible to all waves

    int cur = 0;
    for (int kt = kt0; kt < kt1; ++kt) {
        const int k0 = kt * BKEY;
        const bool havenxt = (kt + 1 < kt1);

        // ---- issue next K into the other buffer (WAR safe: barrier at end of prev iter) ----
        if (havenxt) STAGE_K(cur ^ 1, kt + 1);

        // ---- S = Q K^T on Ksh[cur] : 4 accumulator chains for MFMA ILP ----
        const unsigned short* Ks = &Ksh[cur][0];
        floatx4 s0 = (floatx4){0,0,0,0}, s1 = (floatx4){0,0,0,0};
        floatx4 s0b = (floatx4){0,0,0,0}, s1b = (floatx4){0,0,0,0};
        const int sw = ml & 7;
        __builtin_amdgcn_s_setprio(1);
        #pragma unroll
        for (int kc = 0; kc < 16; kc += 2) {
            const int ch0 = kc * 4 + quad, ch1 = (kc + 1) * 4 + quad;
            bf16x8 a0 = *(bf16x8*)&Ks[ml * DIM + ((ch0 ^ sw) << 3)];
            bf16x8 a1 = *(bf16x8*)&Ks[(16 + ml) * DIM + ((ch0 ^ sw) << 3)];
            bf16x8 b0 = *(bf16x8*)&Ks[ml * DIM + ((ch1 ^ sw) << 3)];
            bf16x8 b1 = *(bf16x8*)&Ks[(16 + ml) * DIM + ((ch1 ^ sw) << 3)];
            s0  = __builtin_amdgcn_mfma_f32_16x16x32_bf16(qf[kc],     a0, s0,  0, 0, 0);
            s1  = __builtin_amdgcn_mfma_f32_16x16x32_bf16(qf[kc],     a1, s1,  0, 0, 0);
            s0b = __builtin_amdgcn_mfma_f32_16x16x32_bf16(qf[kc + 1], b0, s0b, 0, 0, 0);
            s1b = __builtin_amdgcn_mfma_f32_16x16x32_bf16(qf[kc + 1], b1, s1b, 0, 0, 0);
        }
        __builtin_amdgcn_s_setprio(0);
        s0 = s0 + s0b;
        s1 = s1 + s1b;

        // ---- mask + scale in place (log2 domain) ----
        if (kt >= kdiag) {  // diagonal-crossing tiles: apply causal mask
            #pragma unroll
            for (int r = 0; r < 4; ++r) {
                const int qg = q0 + wv * 16 + quad * 4 + r;
                s0[r] = (k0 + ml > qg)      ? -INFINITY : s0[r] * CS;
                s1[r] = (k0 + 16 + ml > qg) ? -INFINITY : s1[r] * CS;
            }
        } else {
            #pragma unroll
            for (int r = 0; r < 4; ++r) { s0[r] *= CS; s1[r] *= CS; }
        }

        // ---- online softmax with defer-max (THR=8 in log2 domain) ----
        float al[4];
        #pragma unroll
        for (int r = 0; r < 4; ++r) {
            float v = fmaxf(s0[r], s1[r]);
            v = fmaxf(v, __shfl_xor(v, 1, 64));
            v = fmaxf(v, __shfl_xor(v, 2, 64));
            v = fmaxf(v, __shfl_xor(v, 4, 64));
            v = fmaxf(v, __shfl_xor(v, 8, 64));
            const float d = v - mrun[r];
            const bool up = d > 8.0f;              // defer small max growth
            al[r]   = up ? __builtin_amdgcn_exp2f(-d) : 1.0f;
            mrun[r] = up ? v : mrun[r];
        }
        #pragma unroll
        for (int r = 0; r < 4; ++r) {
            s0[r] = __builtin_amdgcn_exp2f(s0[r] - mrun[r]);
            s1[r] = __builtin_amdgcn_exp2f(s1[r] - mrun[r]);
            float rs = s0[r] + s1[r];
            rs += __shfl_xor(rs, 1, 64);
            rs += __shfl_xor(rs, 2, 64);
            rs += __shfl_xor(rs, 4, 64);
            rs += __shfl_xor(rs, 8, 64);
            lrun[r] = lrun[r] * al[r] + rs;
        }

        if (al[0] < 1.f || al[1] < 1.f || al[2] < 1.f || al[3] < 1.f) {
            #pragma unroll
            for (int nt = 0; nt < 32; ++nt) {
                acc[nt][0] *= al[0]; acc[nt][1] *= al[1];
                acc[nt][2] *= al[2]; acc[nt][3] *= al[3];
            }
        }

        // ---- P: C-layout -> A-layout via per-wave LDS round trip ----
        unsigned short* Pw = &Psh[wv * (16 * BKEY)];
        #pragma unroll
        for (int r = 0; r < 4; ++r) {
            const int row = quad * 4 + r;
            const int col0 = ml;
            const int col1 = 16 + ml;
            Pw[row * BKEY + ((((col0 >> 3) ^ (row & 3)) << 3) | (col0 & 7))] = f2bf(s0[r]);
            Pw[row * BKEY + ((((col1 >> 3) ^ (row & 3)) << 3) | (col1 & 7))] = f2bf(s1[r]);
        }
        asm volatile("s_waitcnt lgkmcnt(0)" ::: "memory");
        bf16x8 pf = *(bf16x8*)&Pw[ml * BKEY + ((quad ^ (ml & 3)) << 3)];

        // ---- wait V[kt] (issued one phase ago; covered by QK^T+softmax) ----
        if (havenxt) { asm volatile("s_waitcnt vmcnt(4)" ::: "memory"); }  // K[kt+1] stays in flight
        else         { asm volatile("s_waitcnt vmcnt(0)" ::: "memory"); }
        __builtin_amdgcn_s_barrier();      // V[kt] visible to all waves

        // ---- issue next V into the other buffer ----
        if (havenxt) STAGE_V(cur ^ 1, kt + 1);

        // ---- O += P V on Vsh[cur] ----
        const unsigned short* Vs = &Vsh[cur][0];
        __builtin_amdgcn_s_setprio(1);
        #pragma unroll
        for (int nt = 0; nt < 32; ++nt) {
            const int drow = nt * 16 + ml;
            bf16x8 vf = *(bf16x8*)&Vs[drow * BKEY + ((quad ^ (drow & 3)) << 3)];
            acc[nt] = __builtin_amdgcn_mfma_f32_16x16x32_bf16(pf, vf, acc[nt], 0, 0, 0);
        }
        __builtin_amdgcn_s_setprio(0);

        if (havenxt) {
            asm volatile("s_waitcnt vmcnt(4)" ::: "memory");  // K[kt+1] done (V[kt+1] flying)
            __builtin_amdgcn_s_barrier();  // K visible; also releases cur buffers for overwrite
            cur ^= 1;
        }
    }
    #undef STAGE_K
    #undef STAGE_V

    if (!is_split) {
        float inv[4];
        #pragma unroll
        for (int r = 0; r < 4; ++r) inv[r] = 1.f / lrun[r];
        #pragma unroll
        for (int nt = 0; nt < 32; ++nt) {
            #pragma unroll
            for (int r = 0; r < 4; ++r) {
                const int row = q0 + wv * 16 + quad * 4 + r;
                Ob[(size_t)row * DIM + nt * 16 + ml] = acc[nt][r] * inv[r];
            }
        }
    } else {
        const size_t slot = (size_t)(b * NSLOT + j);
        unsigned short* po = PartO + slot * (BQ * DIM);
        #pragma unroll
        for (int nt = 0; nt < 32; ++nt) {
            #pragma unroll
            for (int r = 0; r < 4; ++r) {
                const int prow = wv * 16 + quad * 4 + r;
                po[prow * DIM + nt * 16 + ml] = f2bf(acc[nt][r]);
            }
        }
        if (ml == 0) {
            #pragma unroll
            for (int r = 0; r < 4; ++r) {
                const int prow = wv * 16 + quad * 4 + r;
                Pml[slot * 256 + prow * 2]     = mrun[r];
                Pml[slot * 256 + prow * 2 + 1] = lrun[r];
            }
        }
    }
}

// ---------- merge pass: combine chunk partials per (b, t>=TMIN, rowgroup) ----------
template <int CH, int NSLOT, int TMIN>
__global__ __launch_bounds__(256)
void attn_merge(const unsigned short* __restrict__ PartO,
                const float* __restrict__ Pml,
                float* __restrict__ O)
{
    const int bid = blockIdx.x;            // 8 * (16-TMIN) * 4
    const int b = bid & 7;
    const int u = bid >> 3;
    const int t = TMIN + (u >> 2);
    const int rg = u & 3;                  // 32-row group of the 128-row tile
    const int nc = (4 * t + 4 + CH - 1) / CH;
    int j0 = 0;
    for (int tp = 15; tp > t; --tp) j0 += (4 * tp + 4 + CH - 1) / CH;

    const int row = rg * 32 + (threadIdx.x >> 3);   // 0..127 within q-tile
    const int d0  = (threadIdx.x & 7) * 64;

    float M = -INFINITY;
    for (int cc = 0; cc < nc; ++cc) {
        const size_t slot = (size_t)(b * NSLOT + j0 + cc);
        M = fmaxf(M, Pml[slot * 256 + row * 2]);
    }
    float L = 0.f;
    for (int cc = 0; cc < nc; ++cc) {
        const size_t slot = (size_t)(b * NSLOT + j0 + cc);
        L += Pml[slot * 256 + row * 2 + 1] *
             __builtin_amdgcn_exp2f(Pml[slot * 256 + row * 2] - M);
    }

    float o[64];
    #pragma unroll
    for (int i = 0; i < 64; ++i) o[i] = 0.f;
    for (int cc = 0; cc < nc; ++cc) {
        const size_t slot = (size_t)(b * NSLOT + j0 + cc);
        const float w = __builtin_amdgcn_exp2f(Pml[slot * 256 + row * 2] - M);
        const unsigned short* po = PartO + slot * (BQ * DIM) + (size_t)row * DIM + d0;
        #pragma unroll
        for (int i = 0; i < 8; ++i) {
            ushort8_t v = *(const ushort8_t*)(po + i * 8);
            #pragma unroll
            for (int k2 = 0; k2 < 8; ++k2) o[i * 8 + k2] += w * bf2f(v[k2]);
        }
    }
    const float invL = 1.f / L;
    float* out = O + ((size_t)b * SEQ + (size_t)t * BQ + row) * DIM + d0;
    #pragma unroll
    for (int i = 0; i < 16; ++i) {
        float4 v4 = { o[i*4] * invL, o[i*4+1] * invL, o[i*4+2] * invL, o[i*4+3] * invL };
        *(float4*)(out + i * 4) = v4;
    }
}

extern "C" void kernel_launch(void* const* d_in, const int* in_sizes, int n_in,
                              void* d_out, int out_size, void* d_ws, size_t ws_size,
                              hipStream_t stream) {
    const float* Q = (const float*)d_in[0];
    const float* K = (const float*)d_in[1];
    const float* V = (const float*)d_in[2];
    float* Out = (float*)d_out;

    const size_t elems = (size_t)BSZ * SEQ * DIM;                 // 8.39M
    unsigned short* Kb = (unsigned short*)d_ws;
    unsigned short* Vt = Kb + elems;
    unsigned short* PartO = Vt + elems;
    const size_t kvbytes = 2 * elems * 2;

    prep_kv<<<dim3(4096 + BSZ * (SEQ / BKEY)), dim3(256), 0, stream>>>(K, V, Kb, Vt);

    // CH=6: 96 items/batch, 95 split slots -> 768 blocks (3.0 rounds/CU)
    const size_t need6 = kvbytes + (size_t)BSZ * 95 * BQ * DIM * 2 + (size_t)BSZ * 95 * 256 * 4;
    // CH=8: 72 items/batch, 70 split slots -> 576 blocks (R4 fallback)
    const size_t need8 = kvbytes + (size_t)BSZ * 70 * BQ * DIM * 2 + (size_t)BSZ * 70 * 256 * 4;

    if (ws_size >= need6) {
        float* Pml = (float*)(PartO + (size_t)BSZ * 95 * BQ * DIM);
        attn_fwd<1, 6, 95><<<dim3(BSZ * 96), dim3(512), 0, stream>>>(Q, Kb, Vt, PartO, Pml, Out);
        attn_merge<6, 95, 1><<<dim3(BSZ * 15 * 4), dim3(256), 0, stream>>>(PartO, Pml, Out);
    } else if (ws_size >= need8) {
        float* Pml = (float*)(PartO + (size_t)BSZ * 70 * BQ * DIM);
        attn_fwd<1, 8, 70><<<dim3(BSZ * 72), dim3(512), 0, stream>>>(Q, Kb, Vt, PartO, Pml, Out);
        attn_merge<8, 70, 2><<<dim3(BSZ * 14 * 4), dim3(256), 0, stream>>>(PartO, Pml, Out);
    } else {
        attn_fwd<0, 8, 70><<<dim3(BSZ * 16), dim3(512), 0, stream>>>(Q, Kb, Vt, PartO, (float*)PartO, Out);
    }
}

// Round 7
// 290.913 us; speedup vs baseline: 1.4435x; 1.0851x over previous
//
#include <hip/hip_runtime.h>
#include <math.h>

typedef __bf16 bf16x8 __attribute__((ext_vector_type(8)));
typedef float floatx4 __attribute__((ext_vector_type(4)));
typedef unsigned short ushort8_t __attribute__((ext_vector_type(8)));

#define BSZ 8
#define SEQ 2048
#define DIM 512
#define BKEY 32
#define BQ 128   // 8 waves x 16 rows share each staged K/V tile

__device__ __forceinline__ unsigned short f2bf(float f) {
    unsigned int u = __float_as_uint(f);
    u += 0x7fffu + ((u >> 16) & 1u);   // RNE
    return (unsigned short)(u >> 16);
}
__device__ __forceinline__ float bf2f(unsigned short s) {
    return __uint_as_float(((unsigned int)s) << 16);
}

// async global->LDS, 16B per lane. LDS dest is wave-uniform base + lane*16,
// so LDS layout is linear in chunk index; the bank swizzle is applied by
// permuting the *global* source address within its segment.
#define ASYNC16(g, l) __builtin_amdgcn_global_load_lds( \
    (const __attribute__((address_space(1))) unsigned int*)(g), \
    (__attribute__((address_space(3))) unsigned int*)(l), 16, 0, 0)

// ---------- fused pre-pass: K fp32->bf16 rowmajor  +  V fp32->bf16 tiled-T ----------
// blocks [0,4096): conv K.  blocks [4096,4608): transpose V.
// Vt[(b*64 + ktile)*512*32 + d*32 + key] : each 32-key tile contiguous (32KB)
__global__ __launch_bounds__(256) void prep_kv(const float* __restrict__ K,
                                               const float* __restrict__ V,
                                               unsigned short* __restrict__ Kb,
                                               unsigned short* __restrict__ Vt) {
    if (blockIdx.x < 4096) {
        size_t i = ((size_t)blockIdx.x * 256 + threadIdx.x) * 8;
        float4 a = *(const float4*)(K + i);
        float4 b = *(const float4*)(K + i + 4);
        ushort8_t u;
        u[0]=f2bf(a.x); u[1]=f2bf(a.y); u[2]=f2bf(a.z); u[3]=f2bf(a.w);
        u[4]=f2bf(b.x); u[5]=f2bf(b.y); u[6]=f2bf(b.z); u[7]=f2bf(b.w);
        *(ushort8_t*)(Kb + i) = u;
        return;
    }
    __shared__ unsigned short T[BKEY][DIM + 8];
    const int bid = blockIdx.x - 4096;     // 8*64
    const int b = bid & 7, kb = bid >> 3;
    const float* src = V + ((size_t)b * SEQ + (size_t)kb * BKEY) * DIM;
    const int tid = threadIdx.x;
    #pragma unroll
    for (int i = 0; i < 16; ++i) {
        const int idx = i * 256 + tid;     // float4 idx, 4096 total
        const int key = idx >> 7;
        const int d = (idx & 127) * 4;
        float4 x = *(const float4*)(src + (size_t)key * DIM + d);
        T[key][d]   = f2bf(x.x);
        T[key][d+1] = f2bf(x.y);
        T[key][d+2] = f2bf(x.z);
        T[key][d+3] = f2bf(x.w);
    }
    __syncthreads();
    unsigned short* dst = Vt + (size_t)(b * (SEQ / BKEY) + kb) * DIM * BKEY;
    #pragma unroll
    for (int i = 0; i < 8; ++i) {
        const int cidx = i * 256 + tid;    // 16B chunk 0..2047
        const int d = cidx >> 2;
        const int kc = cidx & 3;
        ushort8_t v;
        #pragma unroll
        for (int k2 = 0; k2 < 8; ++k2) v[k2] = T[kc * 8 + k2][d];
        *(ushort8_t*)(dst + cidx * 8) = v;
    }
}

// Work decomposition (per batch, q-tiles of 128 rows, k-tiles of 32 keys):
//   q-tile t in [0,16) needs nk = 4t+4 k-tiles. Chunks of <=CH k-tiles,
//   cnt(t)=ceil(nk/CH); enumerated t descending (big chunks first), c ascending.
//   CH=6: 96 items/batch (768 blocks = 3.0 rounds/CU, zero tail).

template <int SPLIT, int CH, int NSLOT>
__global__ __launch_bounds__(512, 2)
void attn_fwd(const float* __restrict__ Q,
              const unsigned short* __restrict__ Kb,
              const unsigned short* __restrict__ Vt,
              unsigned short* __restrict__ PartO,
              float* __restrict__ Pml,
              float* __restrict__ O)
{
    // fully double-buffered tiles, deep prefetch: both next-tile stages issue at
    // the TOP of the iteration, so the V-wait is covered by ~1.5 iterations and
    // the K-wait by ~1 iteration of compute. 2 barriers / iteration.
    __shared__ unsigned short Ksh[2][BKEY * DIM];  // chunk i <-> (row=i>>6, cc=i&63), holds ch=cc^(row&7)
    __shared__ unsigned short Vsh[2][DIM * BKEY];  // chunk i <-> (d=i>>2, cc=i&3), holds kc=cc^(d&3)
    __shared__ unsigned short Psh[8 * 16 * BKEY];

    const int tid  = threadIdx.x;
    const int lane = tid & 63;
    const int wv   = tid >> 6;                    // 0..7
    const int ml   = lane & 15;
    const int quad = lane >> 4;

    const int bid = blockIdx.x;
    const int b   = bid & 7;                      // batch -> XCD L2 locality
    const int j   = bid >> 3;
    int t, c;
    if (SPLIT) {
        t = 15; c = j;
        while (true) { const int cnt = (4 * t + 4 + CH - 1) / CH; if (c < cnt) break; c -= cnt; --t; }
    } else { t = 15 - j; c = 0; }
    const int nk  = 4 * t + 4;
    const int kt0 = c * CH;
    const int kt1 = SPLIT ? min(kt0 + CH, nk) : nk;
    const bool is_split = SPLIT && (nk > CH);
    const int q0 = t * BQ;
    const int kdiag = 4 * t;                      // first diagonal-crossing k-tile

    const float* Qb = Q + (size_t)b * SEQ * DIM;
    const unsigned short* Kbb = Kb + (size_t)b * SEQ * DIM;
    const unsigned short* Vtb = Vt + (size_t)b * SEQ * DIM;   // tiled
    float* Ob = O + (size_t)b * SEQ * DIM;

    // ---- Q fragments, A-layout: A[m=lane&15][k=quad*8+j] ----
    bf16x8 qf[16];
    {
        const float* qp = Qb + (size_t)(q0 + wv * 16 + ml) * DIM + quad * 8;
        #pragma unroll
        for (int kc = 0; kc < 16; ++kc) {
            float4 x = *(const float4*)(qp + kc * 32);
            float4 y = *(const float4*)(qp + kc * 32 + 4);
            union { bf16x8 v; unsigned short s[8]; } u;
            u.s[0]=f2bf(x.x); u.s[1]=f2bf(x.y); u.s[2]=f2bf(x.z); u.s[3]=f2bf(x.w);
            u.s[4]=f2bf(y.x); u.s[5]=f2bf(y.y); u.s[6]=f2bf(y.z); u.s[7]=f2bf(y.w);
            qf[kc] = u.v;
        }
    }
    // pin the Q loads before any staging so in-loop vmcnt counting sees only stages
    asm volatile("" ::: "memory");

    floatx4 acc[32];
    #pragma unroll
    for (int i = 0; i < 32; ++i) acc[i] = (floatx4){0.f, 0.f, 0.f, 0.f};
    // finite "minus infinity": keeps exp2(-INF - mrun) == 0 even for rows whose
    // entire chunk is causally masked, avoiding NaN.
    float mrun[4]  = {-1e30f, -1e30f, -1e30f, -1e30f};
    float lpart[4] = {0.f, 0.f, 0.f, 0.f};   // PER-LANE partial row sums; reduced once at epilogue

    const float CS = 1.4426950408889634f * 0.04419417382415922f; // log2(e)/sqrt(512)

    // stage K tile kt_ into buf_ (4 x 16B per thread, swizzled source)
    #define STAGE_K(buf_, kt_) do { \
        const unsigned short* Kt_ = Kbb + (size_t)(kt_) * (BKEY * DIM); \
        unsigned short* Kd_ = &Ksh[(buf_)][0]; \
        _Pragma("unroll") \
        for (int i_ = 0; i_ < 4; ++i_) { \
            const int ci_  = i_ * 512 + tid; \
            const int row_ = ci_ >> 6; \
            const int ch_  = (ci_ & 63) ^ (row_ & 7); \
            ASYNC16(Kt_ + (size_t)row_ * DIM + ch_ * 8, Kd_ + ci_ * 8); \
        } } while (0)
    // stage V tile kt_ from contiguous pre-transposed tile
    #define STAGE_V(buf_, kt_) do { \
        const unsigned short* Vt_ = Vtb + (size_t)(kt_) * (DIM * BKEY); \
        unsigned short* Vd_ = &Vsh[(buf_)][0]; \
        _Pragma("unroll") \
        for (int i_ = 0; i_ < 4; ++i_) { \
            const int ci_ = i_ * 512 + tid; \
            const int d_  = ci_ >> 2; \
            const int kc_ = (ci_ & 3) ^ (d_ & 3); \
            ASYNC16(Vt_ + d_ * BKEY + kc_ * 8, Vd_ + ci_ * 8); \
        } } while (0)

    // ---- prologue: K[kt0]+V[kt0] in flight into buf0; wait K only ----
    STAGE_K(0, kt0);
    STAGE_V(0, kt0);
    asm volatile("s_waitcnt vmcnt(4)" ::: "memory");   // K[kt0] done (V flying)
    __builtin_amdgcn_s_barrier();                      // K visible to all waves

    int cur = 0;
    for (int kt = kt0; kt < kt1; ++kt) {
        const int k0 = kt * BKEY;
        const bool havenxt = (kt + 1 < kt1);

        // ---- deep prefetch: issue BOTH next-tile stages now (WAR safe: the
        // end-of-previous-iteration barrier guaranteed buf cur^1 is consumed) ----
        if (havenxt) { STAGE_K(cur ^ 1, kt + 1); STAGE_V(cur ^ 1, kt + 1); }

        // ---- S = Q K^T on Ksh[cur] : 4 accumulator chains for MFMA ILP ----
        const unsigned short* Ks = &Ksh[cur][0];
        floatx4 s0 = (floatx4){0,0,0,0}, s1 = (floatx4){0,0,0,0};
        floatx4 s0b = (floatx4){0,0,0,0}, s1b = (floatx4){0,0,0,0};
        const int sw = ml & 7;
        __builtin_amdgcn_s_setprio(1);
        #pragma unroll
        for (int kc = 0; kc < 16; kc += 2) {
            const int ch0 = kc * 4 + quad, ch1 = (kc + 1) * 4 + quad;
            bf16x8 a0 = *(bf16x8*)&Ks[ml * DIM + ((ch0 ^ sw) << 3)];
            bf16x8 a1 = *(bf16x8*)&Ks[(16 + ml) * DIM + ((ch0 ^ sw) << 3)];
            bf16x8 b0 = *(bf16x8*)&Ks[ml * DIM + ((ch1 ^ sw) << 3)];
            bf16x8 b1 = *(bf16x8*)&Ks[(16 + ml) * DIM + ((ch1 ^ sw) << 3)];
            s0  = __builtin_amdgcn_mfma_f32_16x16x32_bf16(qf[kc],     a0, s0,  0, 0, 0);
            s1  = __builtin_amdgcn_mfma_f32_16x16x32_bf16(qf[kc],     a1, s1,  0, 0, 0);
            s0b = __builtin_amdgcn_mfma_f32_16x16x32_bf16(qf[kc + 1], b0, s0b, 0, 0, 0);
            s1b = __builtin_amdgcn_mfma_f32_16x16x32_bf16(qf[kc + 1], b1, s1b, 0, 0, 0);
        }
        __builtin_amdgcn_s_setprio(0);
        s0 = s0 + s0b;
        s1 = s1 + s1b;

        // ---- mask + scale in place (log2 domain) ----
        if (kt >= kdiag) {  // diagonal-crossing tiles: apply causal mask
            #pragma unroll
            for (int r = 0; r < 4; ++r) {
                const int qg = q0 + wv * 16 + quad * 4 + r;
                s0[r] = (k0 + ml > qg)      ? -INFINITY : s0[r] * CS;
                s1[r] = (k0 + 16 + ml > qg) ? -INFINITY : s1[r] * CS;
            }
        } else {
            #pragma unroll
            for (int r = 0; r < 4; ++r) { s0[r] *= CS; s1[r] *= CS; }
        }

        // ---- gated online max (T13): skip the butterfly unless some row's local
        // max exceeds mrun+8. Triggers ~once per chunk; common case = 0 shuffles.
        {
            float pm[4];
            bool need = false;
            #pragma unroll
            for (int r = 0; r < 4; ++r) {
                pm[r] = fmaxf(s0[r], s1[r]);
                need = need || (pm[r] > mrun[r] + 8.0f);
            }
            if (__any(need)) {          // wave-uniform branch
                float al[4];
                #pragma unroll
                for (int r = 0; r < 4; ++r) {
                    float v = pm[r];
                    v = fmaxf(v, __shfl_xor(v, 1, 64));
                    v = fmaxf(v, __shfl_xor(v, 2, 64));
                    v = fmaxf(v, __shfl_xor(v, 4, 64));
                    v = fmaxf(v, __shfl_xor(v, 8, 64));
                    const float nm = fmaxf(mrun[r], v);
                    al[r]   = __builtin_amdgcn_exp2f(mrun[r] - nm);
                    mrun[r] = nm;
                    lpart[r] *= al[r];
                }
                #pragma unroll
                for (int nt = 0; nt < 32; ++nt) {
                    acc[nt][0] *= al[0]; acc[nt][1] *= al[1];
                    acc[nt][2] *= al[2]; acc[nt][3] *= al[3];
                }
            }
        }

        // ---- exp + per-lane partial sum (NO butterfly here; deferred to epilogue) ----
        #pragma unroll
        for (int r = 0; r < 4; ++r) {
            s0[r] = __builtin_amdgcn_exp2f(s0[r] - mrun[r]);
            s1[r] = __builtin_amdgcn_exp2f(s1[r] - mrun[r]);
            lpart[r] += s0[r] + s1[r];
        }

        // ---- P: C-layout -> A-layout via per-wave LDS round trip ----
        unsigned short* Pw = &Psh[wv * (16 * BKEY)];
        #pragma unroll
        for (int r = 0; r < 4; ++r) {
            const int row = quad * 4 + r;
            const int col0 = ml;
            const int col1 = 16 + ml;
            Pw[row * BKEY + ((((col0 >> 3) ^ (row & 3)) << 3) | (col0 & 7))] = f2bf(s0[r]);
            Pw[row * BKEY + ((((col1 >> 3) ^ (row & 3)) << 3) | (col1 & 7))] = f2bf(s1[r]);
        }
        asm volatile("s_waitcnt lgkmcnt(0)" ::: "memory");
        bf16x8 pf = *(bf16x8*)&Pw[ml * BKEY + ((quad ^ (ml & 3)) << 3)];

        // ---- wait V[kt] (issued 1.5 iterations ago); K/V[kt+1] stay in flight ----
        if (havenxt) { asm volatile("s_waitcnt vmcnt(8)" ::: "memory"); }
        else         { asm volatile("s_waitcnt vmcnt(0)" ::: "memory"); }
        __builtin_amdgcn_s_barrier();      // V[kt] visible to all waves

        // ---- O += P V on Vsh[cur] ----
        const unsigned short* Vs = &Vsh[cur][0];
        __builtin_amdgcn_s_setprio(1);
        #pragma unroll
        for (int nt = 0; nt < 32; ++nt) {
            const int drow = nt * 16 + ml;
            bf16x8 vf = *(bf16x8*)&Vs[drow * BKEY + ((quad ^ (drow & 3)) << 3)];
            acc[nt] = __builtin_amdgcn_mfma_f32_16x16x32_bf16(pf, vf, acc[nt], 0, 0, 0);
        }
        __builtin_amdgcn_s_setprio(0);

        if (havenxt) {
            asm volatile("s_waitcnt vmcnt(4)" ::: "memory");  // K[kt+1] done (V[kt+1] flying)
            __builtin_amdgcn_s_barrier();  // K visible; releases cur buffers for overwrite
            cur ^= 1;
        }
    }
    #undef STAGE_K
    #undef STAGE_V

    // ---- epilogue: single deferred sum-butterfly for the whole chunk ----
    float lrun[4];
    #pragma unroll
    for (int r = 0; r < 4; ++r) {
        float s = lpart[r];
        s += __shfl_xor(s, 1, 64);
        s += __shfl_xor(s, 2, 64);
        s += __shfl_xor(s, 4, 64);
        s += __shfl_xor(s, 8, 64);
        lrun[r] = s;
    }

    if (!is_split) {
        float inv[4];
        #pragma unroll
        for (int r = 0; r < 4; ++r) inv[r] = 1.f / lrun[r];
        #pragma unroll
        for (int nt = 0; nt < 32; ++nt) {
            #pragma unroll
            for (int r = 0; r < 4; ++r) {
                const int row = q0 + wv * 16 + quad * 4 + r;
                Ob[(size_t)row * DIM + nt * 16 + ml] = acc[nt][r] * inv[r];
            }
        }
    } else {
        const size_t slot = (size_t)(b * NSLOT + j);
        unsigned short* po = PartO + slot * (BQ * DIM);
        #pragma unroll
        for (int nt = 0; nt < 32; ++nt) {
            #pragma unroll
            for (int r = 0; r < 4; ++r) {
                const int prow = wv * 16 + quad * 4 + r;
                po[prow * DIM + nt * 16 + ml] = f2bf(acc[nt][r]);
            }
        }
        if (ml == 0) {
            #pragma unroll
            for (int r = 0; r < 4; ++r) {
                const int prow = wv * 16 + quad * 4 + r;
                Pml[slot * 256 + prow * 2]     = mrun[r];
                Pml[slot * 256 + prow * 2 + 1] = lrun[r];
            }
        }
    }
}

// ---------- merge pass: combine chunk partials per (b, t>=TMIN, rowgroup) ----------
template <int CH, int NSLOT, int TMIN>
__global__ __launch_bounds__(256)
void attn_merge(const unsigned short* __restrict__ PartO,
                const float* __restrict__ Pml,
                float* __restrict__ O)
{
    const int bid = blockIdx.x;            // 8 * (16-TMIN) * 4
    const int b = bid & 7;
    const int u = bid >> 3;
    const int t = TMIN + (u >> 2);
    const int rg = u & 3;                  // 32-row group of the 128-row tile
    const int nc = (4 * t + 4 + CH - 1) / CH;
    int j0 = 0;
    for (int tp = 15; tp > t; --tp) j0 += (4 * tp + 4 + CH - 1) / CH;

    const int row = rg * 32 + (threadIdx.x >> 3);   // 0..127 within q-tile
    const int d0  = (threadIdx.x & 7) * 64;

    float M = -INFINITY;
    for (int cc = 0; cc < nc; ++cc) {
        const size_t slot = (size_t)(b * NSLOT + j0 + cc);
        M = fmaxf(M, Pml[slot * 256 + row * 2]);
    }
    float L = 0.f;
    for (int cc = 0; cc < nc; ++cc) {
        const size_t slot = (size_t)(b * NSLOT + j0 + cc);
        L += Pml[slot * 256 + row * 2 + 1] *
             __builtin_amdgcn_exp2f(Pml[slot * 256 + row * 2] - M);
    }

    float o[64];
    #pragma unroll
    for (int i = 0; i < 64; ++i) o[i] = 0.f;
    for (int cc = 0; cc < nc; ++cc) {
        const size_t slot = (size_t)(b * NSLOT + j0 + cc);
        const float w = __builtin_amdgcn_exp2f(Pml[slot * 256 + row * 2] - M);
        const unsigned short* po = PartO + slot * (BQ * DIM) + (size_t)row * DIM + d0;
        #pragma unroll
        for (int i = 0; i < 8; ++i) {
            ushort8_t v = *(const ushort8_t*)(po + i * 8);
            #pragma unroll
            for (int k2 = 0; k2 < 8; ++k2) o[i * 8 + k2] += w * bf2f(v[k2]);
        }
    }
    const float invL = 1.f / L;
    float* out = O + ((size_t)b * SEQ + (size_t)t * BQ + row) * DIM + d0;
    #pragma unroll
    for (int i = 0; i < 16; ++i) {
        float4 v4 = { o[i*4] * invL, o[i*4+1] * invL, o[i*4+2] * invL, o[i*4+3] * invL };
        *(float4*)(out + i * 4) = v4;
    }
}

extern "C" void kernel_launch(void* const* d_in, const int* in_sizes, int n_in,
                              void* d_out, int out_size, void* d_ws, size_t ws_size,
                              hipStream_t stream) {
    const float* Q = (const float*)d_in[0];
    const float* K = (const float*)d_in[1];
    const float* V = (const float*)d_in[2];
    float* Out = (float*)d_out;

    const size_t elems = (size_t)BSZ * SEQ * DIM;                 // 8.39M
    unsigned short* Kb = (unsigned short*)d_ws;
    unsigned short* Vt = Kb + elems;
    unsigned short* PartO = Vt + elems;
    const size_t kvbytes = 2 * elems * 2;

    prep_kv<<<dim3(4096 + BSZ * (SEQ / BKEY)), dim3(256), 0, stream>>>(K, V, Kb, Vt);

    // CH=6: 96 items/batch, 95 split slots -> 768 blocks (3.0 rounds/CU)
    const size_t need6 = kvbytes + (size_t)BSZ * 95 * BQ * DIM * 2 + (size_t)BSZ * 95 * 256 * 4;
    // CH=8: 72 items/batch, 70 split slots -> 576 blocks (fallback)
    const size_t need8 = kvbytes + (size_t)BSZ * 70 * BQ * DIM * 2 + (size_t)BSZ * 70 * 256 * 4;

    if (ws_size >= need6) {
        float* Pml = (float*)(PartO + (size_t)BSZ * 95 * BQ * DIM);
        attn_fwd<1, 6, 95><<<dim3(BSZ * 96), dim3(512), 0, stream>>>(Q, Kb, Vt, PartO, Pml, Out);
        attn_merge<6, 95, 1><<<dim3(BSZ * 15 * 4), dim3(256), 0, stream>>>(PartO, Pml, Out);
    } else if (ws_size >= need8) {
        float* Pml = (float*)(PartO + (size_t)BSZ * 70 * BQ * DIM);
        attn_fwd<1, 8, 70><<<dim3(BSZ * 72), dim3(512), 0, stream>>>(Q, Kb, Vt, PartO, Pml, Out);
        attn_merge<8, 70, 2><<<dim3(BSZ * 14 * 4), dim3(256), 0, stream>>>(PartO, Pml, Out);
    } else {
        attn_fwd<0, 8, 70><<<dim3(BSZ * 16), dim3(512), 0, stream>>>(Q, Kb, Vt, PartO, (float*)PartO, Out);
    }
}